// Round 7
// baseline (9649.242 us; speedup 1.0000x reference)
//
#include <hip/hip_runtime.h>
#include <hip/hip_bf16.h>
#include <stdint.h>

// Problem constants
#define TT 256
#define BB 64
#define DIN 512
#define RR 2048
#define DOUT 128
#define NTOT (RR*RR)                // 4194304
#define NKEEP 838860                // int(4194304 * (1.0 - 0.8)) in IEEE double
#define BETA 0.9f
#define VTH 1.0f
#define KMAX 576                    // max nonzeros per column (mean 410, sigma 18; 9-sigma guard)

// ---------------- workspace layout ----------------
// drive : float [16384][2048]   @ 0            (134217728 B)
// mask  : u32   [256][64][64]   @ 134217728    (4 MB)  spike bitmask per (t,b)
// flags : u64   [256][64][16]   @ 138412032    (2 MB)  one 128B LINE per (t,b)
// hist  : u32   [256]           @ 140509184
// state : u32   [8]
// cnts  : u32   [2]
// ent   : u32   [8][KMAX][256][2] @ 140513280  (9 MB)  CSC: per (cg,col) packed
//         (val_bits,row) pairs ascending by row
// cnt   : u32   [2048]          @ +9437184     per-column nonzero count
// NOTE: w_rec is masked IN PLACE (harness restores pristine inputs every launch).

#define FLAG_STRIDE 16   // u64s per (t,b) flag slot = 128 B line
#define ENT_OFF 140513280u

__global__ void k_init(uint32_t* __restrict__ p, int n) {
    int i = blockIdx.x * blockDim.x + threadIdx.x;
    int stride = gridDim.x * blockDim.x;
    for (; i < n; i += stride) p[i] = 0u;
}

// ---------------- radix select (4 passes x 8 bits, k-th largest) ----------------
__global__ void k_hist(const float* __restrict__ w_rec, uint32_t* __restrict__ hist,
                       const uint32_t* __restrict__ state, int p) {
    __shared__ uint32_t lh[256];
    lh[threadIdx.x] = 0u;
    __syncthreads();
    uint32_t prefix = (p > 0) ? state[0] : 0u;
    int sh = 24 - 8 * p;
    int i = blockIdx.x * 256 + threadIdx.x;
    int stride = gridDim.x * 256;
    for (; i < NTOT; i += stride) {
        uint32_t u = __float_as_uint(fabsf(w_rec[i]));
        bool ok = (p == 0) || ((u >> (sh + 8)) == prefix);
        if (ok) atomicAdd(&lh[(u >> sh) & 255u], 1u);
    }
    __syncthreads();
    uint32_t v = lh[threadIdx.x];
    if (v) atomicAdd(&hist[threadIdx.x], v);
}

__global__ void k_select(uint32_t* __restrict__ hist, uint32_t* __restrict__ state, int p) {
    __shared__ uint32_t lh[256];
    int tid = threadIdx.x;
    lh[tid] = hist[tid];
    hist[tid] = 0u;            // ready for next pass
    __syncthreads();
    if (tid == 0) {
        uint32_t remaining = (p == 0) ? (uint32_t)NKEEP : state[1];
        int bin = 255;
        for (; bin > 0; --bin) {
            uint32_t c = lh[bin];
            if (c >= remaining) break;
            remaining -= c;
        }
        uint32_t pref = (p == 0) ? 0u : state[0];
        pref = (pref << 8) | (uint32_t)bin;
        state[0] = pref;
        state[1] = remaining;
        if (p == 3) state[2] = pref;   // full 32-bit pattern of threshold value
    }
}

// ---------------- fused: count actives + mask w_rec in place ----------------
__global__ void k_maskcount(float* __restrict__ w, const uint32_t* __restrict__ state,
                            uint32_t* __restrict__ cnts) {
    uint32_t th = state[2];
    uint32_t c = 0;
    int i = blockIdx.x * blockDim.x + threadIdx.x;       // float4 index
    int stride = gridDim.x * blockDim.x;
    for (; i < NTOT / 4; i += stride) {
        float4 v = *(float4*)&w[i * 4];
        if ((__float_as_uint(v.x) & 0x7fffffffu) >= th) c++; else v.x = 0.0f;
        if ((__float_as_uint(v.y) & 0x7fffffffu) >= th) c++; else v.y = 0.0f;
        if ((__float_as_uint(v.z) & 0x7fffffffu) >= th) c++; else v.z = 0.0f;
        if ((__float_as_uint(v.w) & 0x7fffffffu) >= th) c++; else v.w = 0.0f;
        *(float4*)&w[i * 4] = v;
    }
    for (int off = 32; off > 0; off >>= 1) c += __shfl_down(c, off);
    if ((threadIdx.x & 63) == 0 && c) atomicAdd(&cnts[1], c);
}

// ---------------- R6: build CSC per-column nonzero lists (ascending row) ----------------
// ent[cg][j][col][2] = {val_bits, row}; cnt[cg*256+col] = per-column count.
// 8 blocks (one per cg) x 256 threads (col); coalesced 1KB row-slice reads.
__global__ __launch_bounds__(256) void k_csc(const float* __restrict__ w,
                                             uint32_t* __restrict__ ent,
                                             uint32_t* __restrict__ cnt) {
    const int cg = blockIdx.x;       // 0..7
    const int tid = threadIdx.x;     // col within group
    const float* wp = w + (cg << 8) + tid;
    uint32_t* ebase = ent + (size_t)cg * KMAX * 512 + tid * 2;  // stride per j = 512 u32
    int c = 0;
    for (int row = 0; row < RR; ++row) {
        uint32_t vb = __float_as_uint(wp[(size_t)row * RR]);
        if (vb & 0x7fffffffu) {
            if (c < KMAX) {
                uint32_t* e = ebase + (size_t)c * 512;
                e[0] = vb;
                e[1] = (uint32_t)row;
            }
            c++;
        }
    }
    cnt[(cg << 8) + tid] = (uint32_t)(c < KMAX ? c : KMAX);
}

// ---------------- drive GEMM: [16384,512] x [512,2048] + b_in ----------------
__global__ __launch_bounds__(256) void k_drive(const float* __restrict__ x,
                                               const float* __restrict__ w_in,
                                               const float* __restrict__ b_in,
                                               float* __restrict__ drive) {
    __shared__ float As[8][128];
    __shared__ float Bs[8][128];
    const int m0 = blockIdx.x * 128;
    const int n0 = blockIdx.y * 128;
    const int tid = threadIdx.x;
    const int tx = tid & 15, ty = tid >> 4;
    const int ar = tid >> 1;
    const int ak = (tid & 1) * 4;
    const int bk = tid >> 5;
    const int bc = (tid & 31) * 4;
    float acc[8][8];
    #pragma unroll
    for (int i = 0; i < 8; ++i)
        #pragma unroll
        for (int j = 0; j < 8; ++j) acc[i][j] = 0.0f;

    for (int k0 = 0; k0 < DIN; k0 += 8) {
        float4 av = *(const float4*)&x[(m0 + ar) * DIN + k0 + ak];
        float4 bv = *(const float4*)&w_in[(size_t)(k0 + bk) * RR + n0 + bc];
        __syncthreads();
        As[ak + 0][ar] = av.x; As[ak + 1][ar] = av.y;
        As[ak + 2][ar] = av.z; As[ak + 3][ar] = av.w;
        *(float4*)&Bs[bk][bc] = bv;
        __syncthreads();
        #pragma unroll
        for (int kk = 0; kk < 8; ++kk) {
            float a[8], b[8];
            *(float4*)&a[0] = *(const float4*)&As[kk][ty * 8];
            *(float4*)&a[4] = *(const float4*)&As[kk][ty * 8 + 4];
            *(float4*)&b[0] = *(const float4*)&Bs[kk][tx * 8];
            *(float4*)&b[4] = *(const float4*)&Bs[kk][tx * 8 + 4];
            #pragma unroll
            for (int i = 0; i < 8; ++i)
                #pragma unroll
                for (int j = 0; j < 8; ++j)
                    acc[i][j] = fmaf(a[i], b[j], acc[i][j]);
        }
    }
    float bb[8];
    #pragma unroll
    for (int j = 0; j < 8; ++j) bb[j] = b_in[n0 + tx * 8 + j];
    #pragma unroll
    for (int i = 0; i < 8; ++i) {
        size_t row = (size_t)(m0 + ty * 8 + i) * RR + n0 + tx * 8;
        float4 v0, v1;
        v0.x = acc[i][0] + bb[0]; v0.y = acc[i][1] + bb[1];
        v0.z = acc[i][2] + bb[2]; v0.w = acc[i][3] + bb[3];
        v1.x = acc[i][4] + bb[4]; v1.y = acc[i][5] + bb[5];
        v1.z = acc[i][6] + bb[6]; v1.w = acc[i][7] + bb[7];
        *(float4*)&drive[row] = v0;
        *(float4*)&drive[row + 4] = v1;
    }
}

// ---------------- recurrent scan: 256 blocks = 32 batch-PAIRS x 8 col-groups ----------------
// R6 rationale: R5 proved a genuine 48-deep pipeline (VGPR 88) does NOT speed up the
// row-gather -> k_scan is L2-BW-bound (~50 MB/XCD/step = ~85% of 4.3 TB/s ceiling),
// not latency-bound. Only traffic reduction helps. This version:
//   (a) CSC: each lane streams its OWN column's ~410 packed (val,row) nonzeros
//       (no 80%-zero read amplification); ent slice is 1.18 MB/XCD, L2-resident.
//   (b) g=2 batch sharing: one entry stream serves 2 batches (2 spike-bit tests)
//       -> traffic/XCD/step = 32 blk x ~441 x 2KB ~= 29 MB, spike-rate-independent.
//   (c) spike list build eliminated (umask = 64x2 words in LDS, bit-test per entry).
// NUMERICS: per (b,col): a = drive + sum over ascending kept rows of (val & sext(bit))
//   = +val for spiking rows (exact), +0.0f identity for non-spiking kept rows ->
//   value chain identical to all prior passing rounds at every add.
// SYNC: identical protocol; poll 2 flag lines (tid<2), publish 2 bytes.
__global__ __launch_bounds__(256) void k_scan(const uint32_t* __restrict__ ent,
                                              const uint32_t* __restrict__ cnt,
                                              const float* __restrict__ drive,
                                              uint32_t* mask, unsigned long long* flags,
                                              uint32_t* cnts) {
    __shared__ uint32_t umask[64][2];   // [word][batch] spike bits of step t-1
    __shared__ uint32_t s_red[4];

    const int tid = threadIdx.x;
    const int blk = blockIdx.x;       // 0..255
    const int cg = blk & 7;           // col-group -> XCD (blockIdx %8 round-robin)
    const int bg = blk >> 3;          // batch-pair 0..31
    const int b0 = bg * 2, b1 = b0 + 1;
    const int col = (cg << 8) + tid;  // this thread's column
    const int w = tid >> 6;           // wave id 0..3
    const int lane = tid & 63;

    const uint32_t myn = cnt[col];
    const uint2* ep = (const uint2*)(ent + (size_t)cg * KMAX * 512) + tid;  // [j*256]

    float V0 = 0.f, V1 = 0.f;
    uint32_t scnt = 0;
    float dv0 = drive[(size_t)b0 * RR + col];   // t = 0
    float dv1 = drive[(size_t)b1 * RR + col];

    for (int t = 0; t < TT; ++t) {
        float a0 = dv0, a1 = dv1;     // start from drive (bit-exact chain order)
        if (t > 0) {
            if (tid < 2) {
                const unsigned long long* fl =
                    &flags[(size_t)((t - 1) * BB + b0 + tid) * FLAG_STRIDE];
                while (__hip_atomic_load(fl, __ATOMIC_RELAXED, __HIP_MEMORY_SCOPE_AGENT)
                       != ~0ull)
                    __builtin_amdgcn_s_sleep(1);
            }
            __syncthreads();
            if (tid < 64) {   // wave 0: stage both batches' masks into LDS
                uint32_t m0 = __hip_atomic_load(
                    &mask[((size_t)(t - 1) * BB + b0) * 64 + tid],
                    __ATOMIC_RELAXED, __HIP_MEMORY_SCOPE_AGENT);
                uint32_t m1 = __hip_atomic_load(
                    &mask[((size_t)(t - 1) * BB + b1) * 64 + tid],
                    __ATOMIC_RELAXED, __HIP_MEMORY_SCOPE_AGENT);
                umask[tid][0] = m0;
                umask[tid][1] = m1;
            }
            __syncthreads();

            // stream this column's packed nonzeros; 2 predicated exact adds per entry
            #define PROC(e_) { \
                uint32_t row_ = (e_).y; \
                uint2 mm_ = *(const uint2*)&umask[row_ >> 5][0]; \
                uint32_t sh_ = row_ & 31u; \
                uint32_t s0_ = 0u - ((mm_.x >> sh_) & 1u); \
                uint32_t s1_ = 0u - ((mm_.y >> sh_) & 1u); \
                a0 += __uint_as_float((e_).x & s0_); \
                a1 += __uint_as_float((e_).x & s1_); }

            uint32_t j = 0;
            for (; j + 4 <= myn; j += 4) {
                uint2 e0 = ep[(size_t)(j + 0) * 256];
                uint2 e1 = ep[(size_t)(j + 1) * 256];
                uint2 e2 = ep[(size_t)(j + 2) * 256];
                uint2 e3 = ep[(size_t)(j + 3) * 256];
                PROC(e0) PROC(e1) PROC(e2) PROC(e3)
            }
            for (; j < myn; ++j) {
                uint2 e = ep[(size_t)j * 256];
                PROC(e)
            }
            #undef PROC
        }

        V0 = BETA * V0 + a0;          // fma(BETA, V, drive + ascending sum)
        bool sp0 = V0 > VTH;
        if (sp0) V0 -= VTH;
        V1 = BETA * V1 + a1;
        bool sp1 = V1 > VTH;
        if (sp1) V1 -= VTH;

        unsigned long long bal0 = __ballot(sp0);   // 64 cols of this wave
        unsigned long long bal1 = __ballot(sp1);
        if (lane == 0) {
            // u64 mask word (cg*4 + w) covers neurons [cg*256 + w*64, +64)
            __hip_atomic_store(
                (unsigned long long*)&mask[((size_t)t * BB + b0) * 64] + (cg * 4 + w),
                bal0, __ATOMIC_RELAXED, __HIP_MEMORY_SCOPE_AGENT);
            __hip_atomic_store(
                (unsigned long long*)&mask[((size_t)t * BB + b1) * 64] + (cg * 4 + w),
                bal1, __ATOMIC_RELAXED, __HIP_MEMORY_SCOPE_AGENT);
            scnt += (uint32_t)__popcll(bal0) + (uint32_t)__popcll(bal1);
        }
        __syncthreads();   // drains all 4 waves' mask stores (vmcnt(0) before barrier)
        if (tid < 2)       // release: publish flag byte cg for (t,b0) and (t,b1)
            __hip_atomic_store(
                (uint8_t*)&flags[(size_t)(t * BB + b0 + tid) * FLAG_STRIDE] + cg,
                (uint8_t)0xFF, __ATOMIC_RELEASE, __HIP_MEMORY_SCOPE_AGENT);
        __builtin_amdgcn_sched_barrier(0);   // keep prefetch BELOW the release store
        if (t + 1 < TT) {  // prefetch next drive; latency hides under next poll
            dv0 = drive[((size_t)(t + 1) * BB + b0) * RR + col];
            dv1 = drive[((size_t)(t + 1) * BB + b1) * RR + col];
        }
    }

    if (lane == 0) s_red[w] = scnt;
    __syncthreads();
    if (tid == 0) {
        uint32_t s = s_red[0] + s_red[1] + s_red[2] + s_red[3];
        if (s) atomicAdd(&cnts[0], s);
    }
}

// ---------------- head: logits[t,b,:] = s @ w_head + b_head (sparse gather) ----------------
__global__ __launch_bounds__(128) void k_head(const uint32_t* __restrict__ mask,
                                              const float* __restrict__ w_head,
                                              const float* __restrict__ b_head,
                                              float* __restrict__ logits) {
    __shared__ __align__(16) int s_list[RR];   // byte offsets (row*512), 8 KB
    __shared__ int s_n;
    int tb = blockIdx.x;        // t*64 + b
    int tid = threadIdx.x;      // 0..127
    if (tid < 64) {             // wave 0: build ascending spike list
        uint32_t m = mask[tb * 64 + tid];
        int p = __popc(m);
        int off = p;
        #pragma unroll
        for (int d = 1; d < 64; d <<= 1) {
            int o = __shfl_up(off, d);
            if (tid >= d) off += o;
        }
        if (tid == 63) s_n = off;
        int e = off - p;
        int base = tid << 5;
        while (m) {
            int bit = __builtin_ctz(m);
            m &= m - 1;
            s_list[e++] = (base + bit) << 9;   // byte offset = row * DOUT * 4
        }
    }
    __syncthreads();
    const char* Wp = (const char*)(w_head + tid);
    float acc = b_head[tid];
    const int n = s_n;
    int i = 0;
    for (; i + 16 <= n; i += 16) {
        float v[16];
        #pragma unroll
        for (int u = 0; u < 16; u += 4) {
            int4 o = *(const int4*)&s_list[i + u];
            v[u + 0] = *(const float*)(Wp + o.x);
            v[u + 1] = *(const float*)(Wp + o.y);
            v[u + 2] = *(const float*)(Wp + o.z);
            v[u + 3] = *(const float*)(Wp + o.w);
        }
        __builtin_amdgcn_sched_barrier(0);
        #pragma unroll
        for (int j = 0; j < 16; ++j) acc += v[j];   // ascending order
    }
    for (; i < n; ++i) acc += *(const float*)(Wp + s_list[i]);
    logits[(size_t)tb * DOUT + tid] = acc;
}

__global__ __launch_bounds__(128) void k_readout(const float* __restrict__ logits,
                                                 float* __restrict__ readout) {
    int b = blockIdx.x, cidx = threadIdx.x;
    float s = 0.0f;
    for (int t = 0; t < TT; ++t)
        s += logits[(size_t)t * (BB * DOUT) + b * DOUT + cidx];
    readout[b * DOUT + cidx] = s * (1.0f / (float)TT);
}

__global__ void k_scalars(const uint32_t* __restrict__ cnts, float* __restrict__ out) {
    if (threadIdx.x == 0 && blockIdx.x == 0) {
        out[BB * DOUT + TT * BB * DOUT]     = (float)cnts[0] / (float)(TT * BB * RR);
        out[BB * DOUT + TT * BB * DOUT + 1] = (float)cnts[1] / (float)NTOT;
    }
}

extern "C" void kernel_launch(void* const* d_in, const int* in_sizes, int n_in,
                              void* d_out, int out_size, void* d_ws, size_t ws_size,
                              hipStream_t stream) {
    const float* x      = (const float*)d_in[0];
    const float* w_in   = (const float*)d_in[1];
    const float* b_in   = (const float*)d_in[2];
    float*       w_rec  = (float*)d_in[3];        // masked in place (restored each launch)
    const float* w_head = (const float*)d_in[4];
    const float* b_head = (const float*)d_in[5];
    float* out = (float*)d_out;

    float*    drive = (float*)d_ws;
    uint32_t* mask  = (uint32_t*)((char*)d_ws + 134217728u);
    unsigned long long* flags = (unsigned long long*)(mask + (TT * BB * 64));
    uint32_t* hist  = (uint32_t*)(flags + (size_t)TT * BB * FLAG_STRIDE);
    uint32_t* state = hist + 256;
    uint32_t* cnts  = state + 8;
    uint32_t* ent   = (uint32_t*)((char*)d_ws + ENT_OFF);        // 9 MB
    uint32_t* cntc  = ent + (size_t)8 * KMAX * 512;              // 8 KB

    // zero flags + hist + state + cnts (contiguous; mask fully overwritten before read)
    k_init<<<256, 256, 0, stream>>>((uint32_t*)flags,
                                    TT * BB * FLAG_STRIDE * 2 + 256 + 8 + 2);

    for (int p = 0; p < 4; ++p) {
        k_hist<<<1024, 256, 0, stream>>>(w_rec, hist, state, p);
        k_select<<<1, 256, 0, stream>>>(hist, state, p);
    }
    k_maskcount<<<1024, 256, 0, stream>>>(w_rec, state, cnts);

    k_csc<<<8, 256, 0, stream>>>(w_rec, ent, cntc);

    k_drive<<<dim3(128, 16), 256, 0, stream>>>(x, w_in, b_in, drive);

    k_scan<<<256, 256, 0, stream>>>(ent, cntc, drive, mask, flags, cnts);

    k_head<<<TT * BB, 128, 0, stream>>>(mask, w_head, b_head, out + BB * DOUT);
    k_readout<<<BB, 128, 0, stream>>>(out + BB * DOUT, out);
    k_scalars<<<1, 64, 0, stream>>>(cnts, out);
}

// Round 8
// 8215.998 us; speedup vs baseline: 1.1744x; 1.1744x over previous
//
#include <hip/hip_runtime.h>
#include <hip/hip_bf16.h>
#include <stdint.h>

// Problem constants
#define TT 256
#define BB 64
#define DIN 512
#define RR 2048
#define DOUT 128
#define NTOT (RR*RR)                // 4194304
#define NKEEP 838860                // int(4194304 * (1.0 - 0.8)) in IEEE double
#define BETA 0.9f
#define VTH 1.0f
#define KMAX 544                    // max nonzeros/col (mean 410, sigma 18; +7.4 sigma)
#define SPAD (KMAX*2 + 32)          // u32 stride per column stream; 4480 B = 128*35
                                    // (ODD multiple of 128 -> lane streams hit all L1 sets)

// ---------------- workspace layout ----------------
// drive : float [16384][2048]   @ 0            (134217728 B)
// mask  : u32   [256][64][64]   @ 134217728    (4 MB)  spike bitmask per (t,b)
// flags : u64   [256][64][16]   @ 138412032    (2 MB)  one 128B LINE per (t,b)
// hist  : u32   [256]           @ 140509184
// state : u32   [8]   (0: prefix, 1: remaining, 2: thresh bits, 4: nmax)
// cnts  : u32   [2]
// ent   : u32   [2048][SPAD]    @ 140513280    (9.2 MB) CSC per-col packed
//         (val,row) pairs ascending by row, zero-padded to KMAX
// cnt8  : u32   [64][256]       @ ent+9.18MB   (64 KB) per (cg,slice,col) counts
// NOTE: w_rec is masked IN PLACE (harness restores pristine inputs every launch).

#define FLAG_STRIDE 16   // u64s per (t,b) flag slot = 128 B line
#define ENT_OFF 140513280u

__global__ void k_init(uint32_t* __restrict__ p, int n) {
    int i = blockIdx.x * blockDim.x + threadIdx.x;
    int stride = gridDim.x * blockDim.x;
    for (; i < n; i += stride) p[i] = 0u;
}

// ---------------- radix select (4 passes x 8 bits, k-th largest) ----------------
__global__ void k_hist(const float* __restrict__ w_rec, uint32_t* __restrict__ hist,
                       const uint32_t* __restrict__ state, int p) {
    __shared__ uint32_t lh[256];
    lh[threadIdx.x] = 0u;
    __syncthreads();
    uint32_t prefix = (p > 0) ? state[0] : 0u;
    int sh = 24 - 8 * p;
    int i = blockIdx.x * 256 + threadIdx.x;
    int stride = gridDim.x * 256;
    for (; i < NTOT; i += stride) {
        uint32_t u = __float_as_uint(fabsf(w_rec[i]));
        bool ok = (p == 0) || ((u >> (sh + 8)) == prefix);
        if (ok) atomicAdd(&lh[(u >> sh) & 255u], 1u);
    }
    __syncthreads();
    uint32_t v = lh[threadIdx.x];
    if (v) atomicAdd(&hist[threadIdx.x], v);
}

__global__ void k_select(uint32_t* __restrict__ hist, uint32_t* __restrict__ state, int p) {
    __shared__ uint32_t lh[256];
    int tid = threadIdx.x;
    lh[tid] = hist[tid];
    hist[tid] = 0u;            // ready for next pass
    __syncthreads();
    if (tid == 0) {
        uint32_t remaining = (p == 0) ? (uint32_t)NKEEP : state[1];
        int bin = 255;
        for (; bin > 0; --bin) {
            uint32_t c = lh[bin];
            if (c >= remaining) break;
            remaining -= c;
        }
        uint32_t pref = (p == 0) ? 0u : state[0];
        pref = (pref << 8) | (uint32_t)bin;
        state[0] = pref;
        state[1] = remaining;
        if (p == 3) state[2] = pref;   // full 32-bit pattern of threshold value
    }
}

// ---------------- fused: count actives + mask w_rec in place ----------------
__global__ void k_maskcount(float* __restrict__ w, const uint32_t* __restrict__ state,
                            uint32_t* __restrict__ cnts) {
    uint32_t th = state[2];
    uint32_t c = 0;
    int i = blockIdx.x * blockDim.x + threadIdx.x;       // float4 index
    int stride = gridDim.x * blockDim.x;
    for (; i < NTOT / 4; i += stride) {
        float4 v = *(float4*)&w[i * 4];
        if ((__float_as_uint(v.x) & 0x7fffffffu) >= th) c++; else v.x = 0.0f;
        if ((__float_as_uint(v.y) & 0x7fffffffu) >= th) c++; else v.y = 0.0f;
        if ((__float_as_uint(v.z) & 0x7fffffffu) >= th) c++; else v.z = 0.0f;
        if ((__float_as_uint(v.w) & 0x7fffffffu) >= th) c++; else v.w = 0.0f;
        *(float4*)&w[i * 4] = v;
    }
    for (int off = 32; off > 0; off >>= 1) c += __shfl_down(c, off);
    if ((threadIdx.x & 63) == 0 && c) atomicAdd(&cnts[1], c);
}

// ---------------- R7: CSC build, 2-pass, 64 blocks (R6's 8-block version ~400us) ----
// Layout: ent[col][j] -- PER-COLUMN CONTIGUOUS (val,row) pairs ascending by row,
// zero-padded to KMAX. Stride SPAD*4 = 4480 B = 128*35 (odd multiple of 128).
__global__ __launch_bounds__(256) void k_csc_cnt(const float* __restrict__ w,
                                                 uint32_t* __restrict__ cnt8) {
    const int cg = blockIdx.x >> 3, s = blockIdx.x & 7;
    const int tid = threadIdx.x;
    const float* wp = w + (cg << 8) + tid;
    uint32_t c = 0;
    for (int r = s * 256; r < (s + 1) * 256; ++r)
        if (__float_as_uint(wp[(size_t)r * RR]) & 0x7fffffffu) c++;
    cnt8[(blockIdx.x << 8) + tid] = c;
}

__global__ __launch_bounds__(256) void k_csc_fill(const float* __restrict__ w,
                                                  const uint32_t* __restrict__ cnt8,
                                                  uint32_t* __restrict__ ent,
                                                  uint32_t* __restrict__ state) {
    const int cg = blockIdx.x >> 3, s = blockIdx.x & 7;
    const int tid = threadIdx.x;
    const int col = (cg << 8) + tid;
    const float* wp = w + col;
    uint32_t off = 0, tot = 0;
    #pragma unroll
    for (int k = 0; k < 8; ++k) {
        uint32_t c = cnt8[(((cg << 3) | k) << 8) + tid];
        if (k < s) off += c;
        tot += c;
    }
    uint32_t* eb = ent + (size_t)col * SPAD;
    uint32_t c = off;
    for (int r = s * 256; r < (s + 1) * 256; ++r) {
        uint32_t vb = __float_as_uint(wp[(size_t)r * RR]);
        if (vb & 0x7fffffffu) {
            if (c < KMAX) { eb[c * 2] = vb; eb[c * 2 + 1] = (uint32_t)r; }
            c++;
        }
    }
    if (s == 7) {   // one block per cg finalizes: zero-pad tail + publish nmax
        uint32_t cc = tot < KMAX ? tot : KMAX;
        for (uint32_t j = cc; j < KMAX; ++j) { eb[j * 2] = 0u; eb[j * 2 + 1] = 0u; }
        atomicMax(&state[4], cc);
    }
}

// ---------------- drive GEMM: [16384,512] x [512,2048] + b_in ----------------
__global__ __launch_bounds__(256) void k_drive(const float* __restrict__ x,
                                               const float* __restrict__ w_in,
                                               const float* __restrict__ b_in,
                                               float* __restrict__ drive) {
    __shared__ float As[8][128];
    __shared__ float Bs[8][128];
    const int m0 = blockIdx.x * 128;
    const int n0 = blockIdx.y * 128;
    const int tid = threadIdx.x;
    const int tx = tid & 15, ty = tid >> 4;
    const int ar = tid >> 1;
    const int ak = (tid & 1) * 4;
    const int bk = tid >> 5;
    const int bc = (tid & 31) * 4;
    float acc[8][8];
    #pragma unroll
    for (int i = 0; i < 8; ++i)
        #pragma unroll
        for (int j = 0; j < 8; ++j) acc[i][j] = 0.0f;

    for (int k0 = 0; k0 < DIN; k0 += 8) {
        float4 av = *(const float4*)&x[(m0 + ar) * DIN + k0 + ak];
        float4 bv = *(const float4*)&w_in[(size_t)(k0 + bk) * RR + n0 + bc];
        __syncthreads();
        As[ak + 0][ar] = av.x; As[ak + 1][ar] = av.y;
        As[ak + 2][ar] = av.z; As[ak + 3][ar] = av.w;
        *(float4*)&Bs[bk][bc] = bv;
        __syncthreads();
        #pragma unroll
        for (int kk = 0; kk < 8; ++kk) {
            float a[8], b[8];
            *(float4*)&a[0] = *(const float4*)&As[kk][ty * 8];
            *(float4*)&a[4] = *(const float4*)&As[kk][ty * 8 + 4];
            *(float4*)&b[0] = *(const float4*)&Bs[kk][tx * 8];
            *(float4*)&b[4] = *(const float4*)&Bs[kk][tx * 8 + 4];
            #pragma unroll
            for (int i = 0; i < 8; ++i)
                #pragma unroll
                for (int j = 0; j < 8; ++j)
                    acc[i][j] = fmaf(a[i], b[j], acc[i][j]);
        }
    }
    float bb[8];
    #pragma unroll
    for (int j = 0; j < 8; ++j) bb[j] = b_in[n0 + tx * 8 + j];
    #pragma unroll
    for (int i = 0; i < 8; ++i) {
        size_t row = (size_t)(m0 + ty * 8 + i) * RR + n0 + tx * 8;
        float4 v0, v1;
        v0.x = acc[i][0] + bb[0]; v0.y = acc[i][1] + bb[1];
        v0.z = acc[i][2] + bb[2]; v0.w = acc[i][3] + bb[3];
        v1.x = acc[i][4] + bb[4]; v1.y = acc[i][5] + bb[5];
        v1.z = acc[i][6] + bb[6]; v1.w = acc[i][7] + bb[7];
        *(float4*)&drive[row] = v0;
        *(float4*)&drive[row + 4] = v1;
    }
}

// ---------------- recurrent scan: 256 blocks = 32 batch-PAIRS x 8 col-groups ----------------
// R7 rationale: R6's CSC halved traffic but was latency-bound (33us/step): VGPR 24
// (compiler depth ~4), 2KB-strided always-L2 loads, dependent load->LDS-lookup chain.
// Fixes (execution model only, traffic model kept):
//   (a) per-thread CONTIGUOUS entry streams (ent[col][j]): 15/16 of loads are L1 hits
//       (~50cy) -> compiler's shallow depth suffices. Lane working set 64x128B x 4
//       waves = 32 KB = L1; SPAD = odd multiple of 128 B avoids L1-set aliasing.
//   (b) per-step mask EXPANSION: sm[2048][2] full-word masks (0 / 0xFFFFFFFF) built
//       once (~60cy), so per entry = ds_read_b64 + 2 AND + 2 ADD (no shift chain).
//   (c) uniform trip count nmax8 (zero-padded entries: +0.0f exact) -> no divergence.
// NUMERICS: per (b,col): a = drive + ascending kept rows of (val & mask) -- same
// exact chain as R6 (passed); padded zeros append +0.0f at the end.
// SYNC: identical protocol to R6 (passed).
__global__ __launch_bounds__(256) void k_scan(const uint32_t* __restrict__ ent,
                                              const uint32_t* __restrict__ state,
                                              const float* __restrict__ drive,
                                              uint32_t* mask, unsigned long long* flags,
                                              uint32_t* cnts) {
    __shared__ uint32_t umask[64][2];        // [word][batch] raw mask words
    __shared__ __align__(16) uint32_t sm[RR][2];  // expanded per-row masks, 16 KB
    __shared__ uint32_t s_red[4];

    const int tid = threadIdx.x;
    const int blk = blockIdx.x;       // 0..255
    const int cg = blk & 7;           // col-group -> XCD (blockIdx %8 round-robin)
    const int bg = blk >> 3;          // batch-pair 0..31
    const int b0 = bg * 2, b1 = b0 + 1;
    const int col = (cg << 8) + tid;  // this thread's column
    const int w = tid >> 6;           // wave id 0..3
    const int lane = tid & 63;

    const uint32_t nmax8 = (state[4] + 7u) & ~7u;   // uniform, multiple of 8, <= KMAX
    const uint4* ep = (const uint4*)(ent + (size_t)col * SPAD);

    float V0 = 0.f, V1 = 0.f;
    uint32_t scnt = 0;
    float dv0 = drive[(size_t)b0 * RR + col];   // t = 0
    float dv1 = drive[(size_t)b1 * RR + col];

    for (int t = 0; t < TT; ++t) {
        float a0 = dv0, a1 = dv1;     // start from drive (bit-exact chain order)
        if (t > 0) {
            if (tid < 2) {
                const unsigned long long* fl =
                    &flags[(size_t)((t - 1) * BB + b0 + tid) * FLAG_STRIDE];
                while (__hip_atomic_load(fl, __ATOMIC_RELAXED, __HIP_MEMORY_SCOPE_AGENT)
                       != ~0ull)
                    __builtin_amdgcn_s_sleep(1);
            }
            __syncthreads();
            if (tid < 64) {   // wave 0: stage both batches' mask words
                uint32_t m0 = __hip_atomic_load(
                    &mask[((size_t)(t - 1) * BB + b0) * 64 + tid],
                    __ATOMIC_RELAXED, __HIP_MEMORY_SCOPE_AGENT);
                uint32_t m1 = __hip_atomic_load(
                    &mask[((size_t)(t - 1) * BB + b1) * 64 + tid],
                    __ATOMIC_RELAXED, __HIP_MEMORY_SCOPE_AGENT);
                umask[tid][0] = m0;
                umask[tid][1] = m1;
            }
            __syncthreads();
            {   // expand to full-word masks; thread handles rows tid + 256k
                uint32_t sh = 31u - ((uint32_t)tid & 31u);
                #pragma unroll
                for (int k = 0; k < 8; ++k) {
                    int r = tid + (k << 8);
                    uint2 mw = *(const uint2*)&umask[r >> 5][0];
                    sm[r][0] = (uint32_t)((int32_t)(mw.x << sh) >> 31);
                    sm[r][1] = (uint32_t)((int32_t)(mw.y << sh) >> 31);
                }
            }
            __syncthreads();

            // stream this column's packed entries (uint4 = 2 entries)
            #define PROC2(q) { \
                uint2 mA_ = *(const uint2*)&sm[(q).y][0]; \
                uint2 mB_ = *(const uint2*)&sm[(q).w][0]; \
                a0 += __uint_as_float((q).x & mA_.x); \
                a1 += __uint_as_float((q).x & mA_.y); \
                a0 += __uint_as_float((q).z & mB_.x); \
                a1 += __uint_as_float((q).z & mB_.y); }

            const uint32_t n4 = nmax8 >> 1;
            uint32_t j = 0;
            for (; j + 4 <= n4; j += 4) {
                uint4 q0 = ep[j + 0];
                uint4 q1 = ep[j + 1];
                uint4 q2 = ep[j + 2];
                uint4 q3 = ep[j + 3];
                PROC2(q0) PROC2(q1) PROC2(q2) PROC2(q3)
            }
            for (; j < n4; ++j) { uint4 q = ep[j]; PROC2(q) }
            #undef PROC2
        }

        V0 = BETA * V0 + a0;          // fma(BETA, V, drive + ascending sum)
        bool sp0 = V0 > VTH;
        if (sp0) V0 -= VTH;
        V1 = BETA * V1 + a1;
        bool sp1 = V1 > VTH;
        if (sp1) V1 -= VTH;

        unsigned long long bal0 = __ballot(sp0);   // 64 cols of this wave
        unsigned long long bal1 = __ballot(sp1);
        if (lane == 0) {
            // u64 mask word (cg*4 + w) covers neurons [cg*256 + w*64, +64)
            __hip_atomic_store(
                (unsigned long long*)&mask[((size_t)t * BB + b0) * 64] + (cg * 4 + w),
                bal0, __ATOMIC_RELAXED, __HIP_MEMORY_SCOPE_AGENT);
            __hip_atomic_store(
                (unsigned long long*)&mask[((size_t)t * BB + b1) * 64] + (cg * 4 + w),
                bal1, __ATOMIC_RELAXED, __HIP_MEMORY_SCOPE_AGENT);
            scnt += (uint32_t)__popcll(bal0) + (uint32_t)__popcll(bal1);
        }
        __syncthreads();   // drains all 4 waves' mask stores (vmcnt(0) before barrier)
        if (tid < 2)       // release: publish flag byte cg for (t,b0) and (t,b1)
            __hip_atomic_store(
                (uint8_t*)&flags[(size_t)(t * BB + b0 + tid) * FLAG_STRIDE] + cg,
                (uint8_t)0xFF, __ATOMIC_RELEASE, __HIP_MEMORY_SCOPE_AGENT);
        __builtin_amdgcn_sched_barrier(0);   // keep prefetch BELOW the release store
        if (t + 1 < TT) {  // prefetch next drive; latency hides under next poll
            dv0 = drive[((size_t)(t + 1) * BB + b0) * RR + col];
            dv1 = drive[((size_t)(t + 1) * BB + b1) * RR + col];
        }
    }

    if (lane == 0) s_red[w] = scnt;
    __syncthreads();
    if (tid == 0) {
        uint32_t s = s_red[0] + s_red[1] + s_red[2] + s_red[3];
        if (s) atomicAdd(&cnts[0], s);
    }
}

// ---------------- head: logits[t,b,:] = s @ w_head + b_head (sparse gather) ----------------
__global__ __launch_bounds__(128) void k_head(const uint32_t* __restrict__ mask,
                                              const float* __restrict__ w_head,
                                              const float* __restrict__ b_head,
                                              float* __restrict__ logits) {
    __shared__ __align__(16) int s_list[RR];   // byte offsets (row*512), 8 KB
    __shared__ int s_n;
    int tb = blockIdx.x;        // t*64 + b
    int tid = threadIdx.x;      // 0..127
    if (tid < 64) {             // wave 0: build ascending spike list
        uint32_t m = mask[tb * 64 + tid];
        int p = __popc(m);
        int off = p;
        #pragma unroll
        for (int d = 1; d < 64; d <<= 1) {
            int o = __shfl_up(off, d);
            if (tid >= d) off += o;
        }
        if (tid == 63) s_n = off;
        int e = off - p;
        int base = tid << 5;
        while (m) {
            int bit = __builtin_ctz(m);
            m &= m - 1;
            s_list[e++] = (base + bit) << 9;   // byte offset = row * DOUT * 4
        }
    }
    __syncthreads();
    const char* Wp = (const char*)(w_head + tid);
    float acc = b_head[tid];
    const int n = s_n;
    int i = 0;
    for (; i + 16 <= n; i += 16) {
        float v[16];
        #pragma unroll
        for (int u = 0; u < 16; u += 4) {
            int4 o = *(const int4*)&s_list[i + u];
            v[u + 0] = *(const float*)(Wp + o.x);
            v[u + 1] = *(const float*)(Wp + o.y);
            v[u + 2] = *(const float*)(Wp + o.z);
            v[u + 3] = *(const float*)(Wp + o.w);
        }
        __builtin_amdgcn_sched_barrier(0);
        #pragma unroll
        for (int j = 0; j < 16; ++j) acc += v[j];   // ascending order
    }
    for (; i < n; ++i) acc += *(const float*)(Wp + s_list[i]);
    logits[(size_t)tb * DOUT + tid] = acc;
}

__global__ __launch_bounds__(128) void k_readout(const float* __restrict__ logits,
                                                 float* __restrict__ readout) {
    int b = blockIdx.x, cidx = threadIdx.x;
    float s = 0.0f;
    for (int t = 0; t < TT; ++t)
        s += logits[(size_t)t * (BB * DOUT) + b * DOUT + cidx];
    readout[b * DOUT + cidx] = s * (1.0f / (float)TT);
}

__global__ void k_scalars(const uint32_t* __restrict__ cnts, float* __restrict__ out) {
    if (threadIdx.x == 0 && blockIdx.x == 0) {
        out[BB * DOUT + TT * BB * DOUT]     = (float)cnts[0] / (float)(TT * BB * RR);
        out[BB * DOUT + TT * BB * DOUT + 1] = (float)cnts[1] / (float)NTOT;
    }
}

extern "C" void kernel_launch(void* const* d_in, const int* in_sizes, int n_in,
                              void* d_out, int out_size, void* d_ws, size_t ws_size,
                              hipStream_t stream) {
    const float* x      = (const float*)d_in[0];
    const float* w_in   = (const float*)d_in[1];
    const float* b_in   = (const float*)d_in[2];
    float*       w_rec  = (float*)d_in[3];        // masked in place (restored each launch)
    const float* w_head = (const float*)d_in[4];
    const float* b_head = (const float*)d_in[5];
    float* out = (float*)d_out;

    float*    drive = (float*)d_ws;
    uint32_t* mask  = (uint32_t*)((char*)d_ws + 134217728u);
    unsigned long long* flags = (unsigned long long*)(mask + (TT * BB * 64));
    uint32_t* hist  = (uint32_t*)(flags + (size_t)TT * BB * FLAG_STRIDE);
    uint32_t* state = hist + 256;
    uint32_t* cnts  = state + 8;
    uint32_t* ent   = (uint32_t*)((char*)d_ws + ENT_OFF);        // 2048*SPAD u32
    uint32_t* cnt8  = ent + (size_t)2048 * SPAD;                 // 64 KB

    // zero flags + hist + state + cnts (contiguous; mask fully overwritten before read)
    k_init<<<256, 256, 0, stream>>>((uint32_t*)flags,
                                    TT * BB * FLAG_STRIDE * 2 + 256 + 8 + 2);

    for (int p = 0; p < 4; ++p) {
        k_hist<<<1024, 256, 0, stream>>>(w_rec, hist, state, p);
        k_select<<<1, 256, 0, stream>>>(hist, state, p);
    }
    k_maskcount<<<1024, 256, 0, stream>>>(w_rec, state, cnts);

    k_csc_cnt<<<64, 256, 0, stream>>>(w_rec, cnt8);
    k_csc_fill<<<64, 256, 0, stream>>>(w_rec, cnt8, ent, state);

    k_drive<<<dim3(128, 16), 256, 0, stream>>>(x, w_in, b_in, drive);

    k_scan<<<256, 256, 0, stream>>>(ent, state, drive, mask, flags, cnts);

    k_head<<<TT * BB, 128, 0, stream>>>(mask, w_head, b_head, out + BB * DOUT);
    k_readout<<<BB, 128, 0, stream>>>(out + BB * DOUT, out);
    k_scalars<<<1, 64, 0, stream>>>(cnts, out);
}

// Round 9
// 4276.217 us; speedup vs baseline: 2.2565x; 1.9213x over previous
//
#include <hip/hip_runtime.h>
#include <hip/hip_bf16.h>
#include <stdint.h>

// Problem constants
#define TT 256
#define BB 64
#define DIN 512
#define RR 2048
#define DOUT 128
#define NTOT (RR*RR)                // 4194304
#define NKEEP 838860                // int(4194304 * (1.0 - 0.8)) in IEEE double
#define BETA 0.9f
#define VTH 1.0f

// ---------------- workspace layout ----------------
// drive : float [16384][2048]   @ 0            (134217728 B)
// mask  : u32   [256][64][64]   @ 134217728    (4 MB)  spike bitmask per (t,b)
// flags : u64   [256][64][16]   @ +4MB         (2 MB)  one 128B LINE per (t,b)
// hist  : u32   [256]
// state : u32   [8]   (0: prefix, 1: remaining, 2: thresh bits)
// cnts  : u32   [2]   (0: spike count, 1: active count)
// NOTE: w_rec is masked IN PLACE (harness restores pristine inputs every launch).

#define FLAG_STRIDE 16   // u64s per (t,b) flag slot = 128 B line

__global__ void k_init(uint32_t* __restrict__ p, int n) {
    int i = blockIdx.x * blockDim.x + threadIdx.x;
    int stride = gridDim.x * blockDim.x;
    for (; i < n; i += stride) p[i] = 0u;
}

// ---------------- radix select (4 passes x 8 bits, k-th largest) ----------------
__global__ void k_hist(const float* __restrict__ w_rec, uint32_t* __restrict__ hist,
                       const uint32_t* __restrict__ state, int p) {
    __shared__ uint32_t lh[256];
    lh[threadIdx.x] = 0u;
    __syncthreads();
    uint32_t prefix = (p > 0) ? state[0] : 0u;
    int sh = 24 - 8 * p;
    int i = blockIdx.x * 256 + threadIdx.x;
    int stride = gridDim.x * 256;
    for (; i < NTOT; i += stride) {
        uint32_t u = __float_as_uint(fabsf(w_rec[i]));
        bool ok = (p == 0) || ((u >> (sh + 8)) == prefix);
        if (ok) atomicAdd(&lh[(u >> sh) & 255u], 1u);
    }
    __syncthreads();
    uint32_t v = lh[threadIdx.x];
    if (v) atomicAdd(&hist[threadIdx.x], v);
}

__global__ void k_select(uint32_t* __restrict__ hist, uint32_t* __restrict__ state, int p) {
    __shared__ uint32_t lh[256];
    int tid = threadIdx.x;
    lh[tid] = hist[tid];
    hist[tid] = 0u;            // ready for next pass
    __syncthreads();
    if (tid == 0) {
        uint32_t remaining = (p == 0) ? (uint32_t)NKEEP : state[1];
        int bin = 255;
        for (; bin > 0; --bin) {
            uint32_t c = lh[bin];
            if (c >= remaining) break;
            remaining -= c;
        }
        uint32_t pref = (p == 0) ? 0u : state[0];
        pref = (pref << 8) | (uint32_t)bin;
        state[0] = pref;
        state[1] = remaining;
        if (p == 3) state[2] = pref;   // full 32-bit pattern of threshold value
    }
}

// ---------------- fused: count actives + mask w_rec in place ----------------
__global__ void k_maskcount(float* __restrict__ w, const uint32_t* __restrict__ state,
                            uint32_t* __restrict__ cnts) {
    uint32_t th = state[2];
    uint32_t c = 0;
    int i = blockIdx.x * blockDim.x + threadIdx.x;       // float4 index
    int stride = gridDim.x * blockDim.x;
    for (; i < NTOT / 4; i += stride) {
        float4 v = *(float4*)&w[i * 4];
        if ((__float_as_uint(v.x) & 0x7fffffffu) >= th) c++; else v.x = 0.0f;
        if ((__float_as_uint(v.y) & 0x7fffffffu) >= th) c++; else v.y = 0.0f;
        if ((__float_as_uint(v.z) & 0x7fffffffu) >= th) c++; else v.z = 0.0f;
        if ((__float_as_uint(v.w) & 0x7fffffffu) >= th) c++; else v.w = 0.0f;
        *(float4*)&w[i * 4] = v;
    }
    for (int off = 32; off > 0; off >>= 1) c += __shfl_down(c, off);
    if ((threadIdx.x & 63) == 0 && c) atomicAdd(&cnts[1], c);
}

// ---------------- drive GEMM: [16384,512] x [512,2048] + b_in ----------------
__global__ __launch_bounds__(256) void k_drive(const float* __restrict__ x,
                                               const float* __restrict__ w_in,
                                               const float* __restrict__ b_in,
                                               float* __restrict__ drive) {
    __shared__ float As[8][128];
    __shared__ float Bs[8][128];
    const int m0 = blockIdx.x * 128;
    const int n0 = blockIdx.y * 128;
    const int tid = threadIdx.x;
    const int tx = tid & 15, ty = tid >> 4;
    const int ar = tid >> 1;
    const int ak = (tid & 1) * 4;
    const int bk = tid >> 5;
    const int bc = (tid & 31) * 4;
    float acc[8][8];
    #pragma unroll
    for (int i = 0; i < 8; ++i)
        #pragma unroll
        for (int j = 0; j < 8; ++j) acc[i][j] = 0.0f;

    for (int k0 = 0; k0 < DIN; k0 += 8) {
        float4 av = *(const float4*)&x[(m0 + ar) * DIN + k0 + ak];
        float4 bv = *(const float4*)&w_in[(size_t)(k0 + bk) * RR + n0 + bc];
        __syncthreads();
        As[ak + 0][ar] = av.x; As[ak + 1][ar] = av.y;
        As[ak + 2][ar] = av.z; As[ak + 3][ar] = av.w;
        *(float4*)&Bs[bk][bc] = bv;
        __syncthreads();
        #pragma unroll
        for (int kk = 0; kk < 8; ++kk) {
            float a[8], b[8];
            *(float4*)&a[0] = *(const float4*)&As[kk][ty * 8];
            *(float4*)&a[4] = *(const float4*)&As[kk][ty * 8 + 4];
            *(float4*)&b[0] = *(const float4*)&Bs[kk][tx * 8];
            *(float4*)&b[4] = *(const float4*)&Bs[kk][tx * 8 + 4];
            #pragma unroll
            for (int i = 0; i < 8; ++i)
                #pragma unroll
                for (int j = 0; j < 8; ++j)
                    acc[i][j] = fmaf(a[i], b[j], acc[i][j]);
        }
    }
    float bb[8];
    #pragma unroll
    for (int j = 0; j < 8; ++j) bb[j] = b_in[n0 + tx * 8 + j];
    #pragma unroll
    for (int i = 0; i < 8; ++i) {
        size_t row = (size_t)(m0 + ty * 8 + i) * RR + n0 + tx * 8;
        float4 v0, v1;
        v0.x = acc[i][0] + bb[0]; v0.y = acc[i][1] + bb[1];
        v0.z = acc[i][2] + bb[2]; v0.w = acc[i][3] + bb[3];
        v1.x = acc[i][4] + bb[4]; v1.y = acc[i][5] + bb[5];
        v1.z = acc[i][6] + bb[6]; v1.w = acc[i][7] + bb[7];
        *(float4*)&drive[row] = v0;
        *(float4*)&drive[row + 4] = v1;
    }
}

// ---------------- recurrent scan: 512 blocks = 64 batches x 8 col-groups ----------------
// Block = (batch b, 256-col group cg); cg = blk&7 keeps a col-group on one XCD so its
// 2 MB w_rec slice stays L2-resident. lane = column (1 V per lane), 4 waves walk the
// shared spike list.
// VERIFIED BEST (Round-4 bench: total 4283 us, k_scan 3638 us). Post-hoc knowledge:
// R5's genuine 48-deep DMA pipeline did NOT beat this => k_scan is L2-BW-bound
// (~46 MB/XCD/step ~= 11.6 us at 4.3 TB/s + ~2.6 us sync = 14.2 us/step measured).
// The 64-deep batch below compiles to effective depth ~13 (VGPR 48) which saturates
// the BW regime; deeper is provably null, traffic-reduction (CSC, R6-R8) is
// execution-bound and slower.
// SYNC: relaxed-atomic polls ONLY; flags padded 1 line/(t,b); flag store is release.
// NUMERICS: per-(b,c) chain = drive-first + ascending-row adds + V=fma(BETA,V,acc) --
// bit-identical to all prior passing rounds.
__global__ __launch_bounds__(256, 2) void k_scan(const float* __restrict__ w_rec,
                                                 const float* __restrict__ drive,
                                                 uint32_t* mask, unsigned long long* flags,
                                                 uint32_t* cnts) {
    __shared__ __align__(16) int s_list[RR];   // byte offsets (row*8192), 8 KB
    __shared__ int s_n;
    __shared__ uint32_t s_red[4];

    const int tid = threadIdx.x;
    const int blk = blockIdx.x;       // 0..511
    const int cg = blk & 7;           // col-group -> XCD (blockIdx %8 round-robin)
    const int b = blk >> 3;           // batch 0..63
    const int col = (cg << 8) + tid;  // this thread's column
    const int w = tid >> 6;           // wave id 0..3
    const int lane = tid & 63;
    const char* Wp = (const char*)(w_rec + col);

    float V = 0.f;
    uint32_t scnt = 0;
    float dv = drive[(size_t)b * RR + col];   // t = 0

    for (int t = 0; t < TT; ++t) {
        float a = dv;                 // start from drive (bit-exact chain order)
        if (t > 0) {
            if (tid == 0) {
                const unsigned long long* fl =
                    &flags[(size_t)((t - 1) * BB + b) * FLAG_STRIDE];
                while (__hip_atomic_load(fl, __ATOMIC_RELAXED, __HIP_MEMORY_SCOPE_AGENT)
                       != ~0ull)
                    __builtin_amdgcn_s_sleep(1);
            }
            __syncthreads();
            if (tid < 64) {   // wave 0: load batch mask, build ascending spike list
                uint32_t m = __hip_atomic_load(&mask[((size_t)(t - 1) * BB + b) * 64 + tid],
                                               __ATOMIC_RELAXED, __HIP_MEMORY_SCOPE_AGENT);
                int p = __popc(m);
                int off = p;
                #pragma unroll
                for (int d = 1; d < 64; d <<= 1) {
                    int o = __shfl_up(off, d);
                    if (tid >= d) off += o;
                }
                if (tid == 63) s_n = off;
                int e = off - p;
                int base = tid << 5;
                while (m) {
                    int bit = __builtin_ctz(m);
                    m &= m - 1;
                    s_list[e++] = (base + bit) << 13;   // byte offset = row * 8192
                }
            }
            __syncthreads();
            const int n = s_n;
            int i = 0;
            for (; i + 64 <= n; i += 64) {   // 64 loads issued, THEN 64 adds (pinned)
                float v[64];
                #pragma unroll
                for (int u = 0; u < 64; u += 4) {
                    int4 o = *(const int4*)&s_list[i + u];   // LDS broadcast b128
                    v[u + 0] = *(const float*)(Wp + o.x);
                    v[u + 1] = *(const float*)(Wp + o.y);
                    v[u + 2] = *(const float*)(Wp + o.z);
                    v[u + 3] = *(const float*)(Wp + o.w);
                }
                __builtin_amdgcn_sched_barrier(0);   // all 64 loads precede all adds
                #pragma unroll
                for (int j = 0; j < 64; ++j) a += v[j];    // ascending order
            }
            for (; i + 16 <= n; i += 16) {
                float v[16];
                #pragma unroll
                for (int u = 0; u < 16; u += 4) {
                    int4 o = *(const int4*)&s_list[i + u];
                    v[u + 0] = *(const float*)(Wp + o.x);
                    v[u + 1] = *(const float*)(Wp + o.y);
                    v[u + 2] = *(const float*)(Wp + o.z);
                    v[u + 3] = *(const float*)(Wp + o.w);
                }
                __builtin_amdgcn_sched_barrier(0);
                #pragma unroll
                for (int j = 0; j < 16; ++j) a += v[j];
            }
            for (; i + 4 <= n; i += 4) {
                int4 o = *(const int4*)&s_list[i];
                float v0 = *(const float*)(Wp + o.x);
                float v1 = *(const float*)(Wp + o.y);
                float v2 = *(const float*)(Wp + o.z);
                float v3 = *(const float*)(Wp + o.w);
                a += v0; a += v1; a += v2; a += v3;
            }
            for (; i < n; ++i) a += *(const float*)(Wp + s_list[i]);
        }

        V = BETA * V + a;             // fma(BETA, V, drive + ascending sum)
        bool sp = V > VTH;
        if (sp) V -= VTH;

        unsigned long long bal = __ballot(sp);   // 64 cols of this wave
        if (lane == 0) {
            // u64 mask word (cg*4 + w) covers neurons [cg*256 + w*64, +64)
            __hip_atomic_store(
                (unsigned long long*)&mask[((size_t)t * BB + b) * 64] + (cg * 4 + w),
                bal, __ATOMIC_RELAXED, __HIP_MEMORY_SCOPE_AGENT);
            scnt += (uint32_t)__popcll(bal);
        }
        __syncthreads();   // drains all 4 waves' mask stores (vmcnt(0) before barrier)
        if (tid == 0)      // release: publish flag byte cg for (t,b)
            __hip_atomic_store(
                (uint8_t*)&flags[(size_t)(t * BB + b) * FLAG_STRIDE] + cg, (uint8_t)0xFF,
                __ATOMIC_RELEASE, __HIP_MEMORY_SCOPE_AGENT);
        __builtin_amdgcn_sched_barrier(0);   // keep prefetch BELOW the release store
        if (t + 1 < TT)    // prefetch next drive; latency hides under next poll+list
            dv = drive[((size_t)(t + 1) * BB + b) * RR + col];
    }

    if (lane == 0) s_red[w] = scnt;
    __syncthreads();
    if (tid == 0) {
        uint32_t s = s_red[0] + s_red[1] + s_red[2] + s_red[3];
        if (s) atomicAdd(&cnts[0], s);
    }
}

// ---------------- head: logits[t,b,:] = s @ w_head + b_head (sparse gather) ----------------
__global__ __launch_bounds__(128) void k_head(const uint32_t* __restrict__ mask,
                                              const float* __restrict__ w_head,
                                              const float* __restrict__ b_head,
                                              float* __restrict__ logits) {
    __shared__ __align__(16) int s_list[RR];   // byte offsets (row*512), 8 KB
    __shared__ int s_n;
    int tb = blockIdx.x;        // t*64 + b
    int tid = threadIdx.x;      // 0..127
    if (tid < 64) {             // wave 0: build ascending spike list
        uint32_t m = mask[tb * 64 + tid];
        int p = __popc(m);
        int off = p;
        #pragma unroll
        for (int d = 1; d < 64; d <<= 1) {
            int o = __shfl_up(off, d);
            if (tid >= d) off += o;
        }
        if (tid == 63) s_n = off;
        int e = off - p;
        int base = tid << 5;
        while (m) {
            int bit = __builtin_ctz(m);
            m &= m - 1;
            s_list[e++] = (base + bit) << 9;   // byte offset = row * DOUT * 4
        }
    }
    __syncthreads();
    const char* Wp = (const char*)(w_head + tid);
    float acc = b_head[tid];
    const int n = s_n;
    int i = 0;
    for (; i + 16 <= n; i += 16) {
        float v[16];
        #pragma unroll
        for (int u = 0; u < 16; u += 4) {
            int4 o = *(const int4*)&s_list[i + u];
            v[u + 0] = *(const float*)(Wp + o.x);
            v[u + 1] = *(const float*)(Wp + o.y);
            v[u + 2] = *(const float*)(Wp + o.z);
            v[u + 3] = *(const float*)(Wp + o.w);
        }
        __builtin_amdgcn_sched_barrier(0);
        #pragma unroll
        for (int j = 0; j < 16; ++j) acc += v[j];   // ascending order
    }
    for (; i < n; ++i) acc += *(const float*)(Wp + s_list[i]);
    logits[(size_t)tb * DOUT + tid] = acc;
}

__global__ __launch_bounds__(128) void k_readout(const float* __restrict__ logits,
                                                 float* __restrict__ readout) {
    int b = blockIdx.x, cidx = threadIdx.x;
    float s = 0.0f;
    for (int t = 0; t < TT; ++t)
        s += logits[(size_t)t * (BB * DOUT) + b * DOUT + cidx];
    readout[b * DOUT + cidx] = s * (1.0f / (float)TT);
}

__global__ void k_scalars(const uint32_t* __restrict__ cnts, float* __restrict__ out) {
    if (threadIdx.x == 0 && blockIdx.x == 0) {
        out[BB * DOUT + TT * BB * DOUT]     = (float)cnts[0] / (float)(TT * BB * RR);
        out[BB * DOUT + TT * BB * DOUT + 1] = (float)cnts[1] / (float)NTOT;
    }
}

extern "C" void kernel_launch(void* const* d_in, const int* in_sizes, int n_in,
                              void* d_out, int out_size, void* d_ws, size_t ws_size,
                              hipStream_t stream) {
    const float* x      = (const float*)d_in[0];
    const float* w_in   = (const float*)d_in[1];
    const float* b_in   = (const float*)d_in[2];
    float*       w_rec  = (float*)d_in[3];        // masked in place (restored each launch)
    const float* w_head = (const float*)d_in[4];
    const float* b_head = (const float*)d_in[5];
    float* out = (float*)d_out;

    float*    drive = (float*)d_ws;
    uint32_t* mask  = (uint32_t*)((char*)d_ws + 134217728u);
    unsigned long long* flags = (unsigned long long*)(mask + (TT * BB * 64));
    uint32_t* hist  = (uint32_t*)(flags + (size_t)TT * BB * FLAG_STRIDE);
    uint32_t* state = hist + 256;
    uint32_t* cnts  = state + 8;

    // zero flags + hist + state + cnts (contiguous; mask fully overwritten before read)
    k_init<<<256, 256, 0, stream>>>((uint32_t*)flags,
                                    TT * BB * FLAG_STRIDE * 2 + 256 + 8 + 2);

    for (int p = 0; p < 4; ++p) {
        k_hist<<<1024, 256, 0, stream>>>(w_rec, hist, state, p);
        k_select<<<1, 256, 0, stream>>>(hist, state, p);
    }
    k_maskcount<<<1024, 256, 0, stream>>>(w_rec, state, cnts);

    k_drive<<<dim3(128, 16), 256, 0, stream>>>(x, w_in, b_in, drive);

    k_scan<<<512, 256, 0, stream>>>(w_rec, drive, mask, flags, cnts);

    k_head<<<TT * BB, 128, 0, stream>>>(mask, w_head, b_head, out + BB * DOUT);
    k_readout<<<BB, 128, 0, stream>>>(out + BB * DOUT, out);
    k_scalars<<<1, 64, 0, stream>>>(cnts, out);
}